// Round 6
// baseline (318.704 us; speedup 1.0000x reference)
//
#include <hip/hip_runtime.h>
#include <stdint.h>

#define N 8192
#define NCLS 80
#define NWD 128             // keep-mask words (8192 bits)
#define PAIR_CAP (1 << 20)  // 1M edges (4 MB); expected E ~ 2K
#define K2_GX 128
#define K2_GY 8
#define K2_BLOCKS (K2_GX * K2_GY)

// ---------------- K1: per-box prep (original index space) ---------------
// 8 threads per box: argmax-80 (first-max wins), corners/area/conf/cls/valid.
__global__ void __launch_bounds__(256) k_prep(
    const float* __restrict__ box, const float* __restrict__ conf,
    const float* __restrict__ logits,
    float4* __restrict__ sbox, float4* __restrict__ smeta,
    unsigned char* __restrict__ vb,
    int* __restrict__ paircnt, int* __restrict__ done)
{
#pragma clang fp contract(off)
    int gid = blockIdx.x * 256 + threadIdx.x;      // 0..65535
    if (gid == 0) { *paircnt = 0; *done = 0; }
    int i = gid >> 3, s = gid & 7;
    const float4* lp = (const float4*)(logits + (size_t)i * NCLS);
    float best = -INFINITY; int bi = 0;
#pragma unroll
    for (int k2 = 0; k2 < 3; ++k2) {
        int c4 = s + 8 * k2;                       // 20 float4 chunks / 8 lanes
        if (c4 < 20) {
            float4 v = lp[c4]; int b = c4 * 4;
            if (v.x > best) { best = v.x; bi = b; }
            if (v.y > best) { best = v.y; bi = b + 1; }
            if (v.z > best) { best = v.z; bi = b + 2; }
            if (v.w > best) { best = v.w; bi = b + 3; }
        }
    }
    // 8-lane butterfly; ties -> lowest index (jnp first-max)
#pragma unroll
    for (int off = 1; off < 8; off <<= 1) {
        float ob = __shfl_xor(best, off, 8);
        int   oi = __shfl_xor(bi, off, 8);
        if (ob > best || (ob == best && oi < bi)) { best = ob; bi = oi; }
    }
    if (s == 0) {
        float c = conf[i];
        bool valid = c > 0.5f;
        float4 b = ((const float4*)box)[i];        // x, y, w, h
        float hw = b.z * 0.5f, hh = b.w * 0.5f;    // == w/2 exactly
        sbox[i]  = make_float4(b.x - hw, b.y - hh, b.x + hw, b.y + hh);
        smeta[i] = make_float4(b.z * b.w, c, (float)bi, valid ? 1.0f : 0.0f);
        vb[i] = valid ? 1 : 0;
    }
}

// ---------------- K2: pairs + last-block Jacobi scan + outputs ----------
// Wave-tiles 64x64 over upper-tri of 8192^2. Edge u->v directed by
// (conf desc, idx asc) == jnp stable argsort of -conf. Last finishing
// block (threadfence/done-counter protocol) runs the fixpoint and writes
// all outputs (L2-hot, ~2 us) -- cheaper than another dispatch gap.
__global__ void __launch_bounds__(1024) k_main(
    const float* __restrict__ box, const float* __restrict__ conf,
    const float4* __restrict__ sbox, const float4* __restrict__ smeta,
    const unsigned char* __restrict__ vb,
    unsigned int* __restrict__ pairs, int* __restrict__ paircnt,
    int* __restrict__ done, float* __restrict__ out)
{
#pragma clang fp contract(off)
    __shared__ float4 cbox[16][64];
    __shared__ float4 cmeta[16][64];
    int tid = threadIdx.x;
    int wv = tid >> 6, lane = tid & 63;
    int ti = blockIdx.x;                  // row tile (64 rows)
    int tg = blockIdx.y;                  // col group (16 tiles of 64)
    int tj = 16 * tg + wv;

    if (16 * tg + 15 >= ti && tj >= ti) { // this wave has an upper-tri tile
        int rbase = ti << 6, cbase = tj << 6;
        int c = cbase + lane;
        cbox[wv][lane]  = sbox[c];
        cmeta[wv][lane] = smeta[c];       // wave-private LDS: no barrier
        int r = rbase + lane;
        float4 rb = sbox[r];
        float4 rm = smeta[r];
        bool rvalid = (rm.w != 0.0f);
        float rar = rm.x, rconf = rm.y;
        int rcls = (int)rm.z;
        for (int k = 0; k < 64; ++k) {
            int c2 = cbase + k;
            float4 cm2 = cmeta[wv][k];    // same-address broadcast
            bool pre = rvalid & (cm2.w != 0.0f) & ((int)cm2.z == rcls) & (c2 > r);
            if (__any(pre)) {             // ~18% of iters reach geometry
                float4 c4 = cbox[wv][k];
                // exact float32 op order of the reference:
                float iw = fminf(rb.z, c4.z) - fmaxf(rb.x, c4.x);
                iw = fmaxf(iw, 0.0f);
                float ih = fminf(rb.w, c4.w) - fmaxf(rb.y, c4.y);
                ih = fmaxf(ih, 0.0f);
                // iw<=0 or ih<=0 => inter==0 => iou<=0 (or NaN) => no edge
                pre = pre & (iw > 0.0f) & (ih > 0.0f);
                if (__any(pre)) {
                    float inter = iw * ih;
                    float uni = rar + cm2.x - inter;
                    float iou = __fdiv_rn(inter, uni);   // IEEE divide
                    if (pre && iou > 0.5f) {
                        // earlier key suppresses later: conf desc, idx asc tie
                        unsigned int u, v;
                        if (rconf >= cm2.y) { u = r; v = c2; }
                        else                { u = c2; v = r; }
                        int idx = atomicAdd(paircnt, 1);
                        if (idx < PAIR_CAP) pairs[idx] = (u << 13) | v;
                    }
                }
            }
        }
    }

    // ---- completion protocol: last block does the serial tail ----
    __shared__ int lastflag;
    __threadfence();                      // release this thread's pair writes
    __syncthreads();
    if (tid == 0) {
        int old = atomicAdd(done, 1);
        lastflag = (old == K2_BLOCKS - 1);
    }
    __syncthreads();
    if (!lastflag) return;
    __threadfence();                      // acquire: see all blocks' pairs

    // ---- Jacobi fixpoint over sparse suppression DAG (in LDS) ----
    __shared__ unsigned long long keep[NWD], sn[NWD], vmw[NWD];
    __shared__ int chg;
    int E = *paircnt; if (E > PAIR_CAP) E = PAIR_CAP;
    if (tid < NWD) {
        const unsigned long long* vb8 = (const unsigned long long*)vb;
        unsigned long long w = 0ULL;
#pragma unroll
        for (int j = 0; j < 8; ++j) {
            unsigned long long x = vb8[tid * 8 + j];     // 8 bytes in {0,1}
            unsigned long long b8 = (x * 0x0102040810204080ULL) >> 56;
            w |= b8 << (8 * j);
        }
        vmw[tid] = w;
        keep[tid] = w;                    // K0 = valid
    }
    __syncthreads();
    for (int round = 0; round < 8192; ++round) {
        if (tid < NWD) sn[tid] = 0ULL;
        if (tid == 0) chg = 0;
        __syncthreads();
        for (int e = tid; e < E; e += 1024) {
            unsigned int p = pairs[e];
            int u = p >> 13, v = p & 8191;
            if ((keep[u >> 6] >> (u & 63)) & 1ULL)
                atomicOr(&sn[v >> 6], 1ULL << (v & 63));
        }
        __syncthreads();
        if (tid < NWD) {
            unsigned long long nk = vmw[tid] & ~sn[tid];
            if (nk != keep[tid]) { keep[tid] = nk; chg = 1; }
        }
        __syncthreads();
        if (!chg) break;                  // unique fixpoint == greedy scan
    }

    // ---- outputs (single block, L2-hot) ----
    for (int i = tid; i < N; i += 1024) {
        float m = (float)((keep[i >> 6] >> (i & 63)) & 1ULL);
        float4 b = ((const float4*)box)[i];
        float4 sm = smeta[i];             // y=conf, z=cls
        out[i * 5 + 0] = b.x * m;
        out[i * 5 + 1] = b.y * m;
        out[i * 5 + 2] = b.z * m;
        out[i * 5 + 3] = b.w * m;
        out[i * 5 + 4] = sm.y * m;
        out[5 * N + i] = sm.z;
        out[6 * N + i] = m;
    }
}

// ---------------- launch -------------------------------------------------
extern "C" void kernel_launch(void* const* d_in, const int* in_sizes, int n_in,
                              void* d_out, int out_size, void* d_ws, size_t ws_size,
                              hipStream_t stream) {
    const float* box    = (const float*)d_in[0];
    const float* conf   = (const float*)d_in[1];
    const float* logits = (const float*)d_in[2];
    float* out = (float*)d_out;

    char* ws = (char*)d_ws;
    float4* sbox  = (float4*)(ws + 0);                    // 128 KB
    float4* smeta = (float4*)(ws + 131072);               // 128 KB
    unsigned char* vb = (unsigned char*)(ws + 262144);    // 8 KB
    int* paircnt  = (int*)(ws + 270336);
    int* done     = (int*)(ws + 270464);                  // separate line
    unsigned int* pairs = (unsigned int*)(ws + 278528);   // 4 MB

    k_prep<<<256, 256, 0, stream>>>(box, conf, logits, sbox, smeta, vb,
                                    paircnt, done);
    k_main<<<dim3(K2_GX, K2_GY), 1024, 0, stream>>>(box, conf, sbox, smeta, vb,
                                                    pairs, paircnt, done, out);
}

// Round 7
// 143.599 us; speedup vs baseline: 2.2194x; 2.2194x over previous
//
#include <hip/hip_runtime.h>
#include <stdint.h>

#define N 8192
#define NCLS 80
#define NWD 128             // keep-mask words (8192 bits)
#define PAIR_CAP (1 << 20)  // 1M edges (4 MB); expected E ~ 2K
#define K2_BLOCKS 528       // upper-tri of 32x32 tiles (256x256 boxes each)

// ---------------- K1: argmax + valid-compaction --------------------------
// 8 threads per box. Lane s==0 of each group writes compacted arrays
// (arbitrary order -- edge direction comes from the 64-bit key).
__global__ void __launch_bounds__(256) k_prep(
    const float* __restrict__ box, const float* __restrict__ conf,
    const float* __restrict__ logits,
    int* __restrict__ cnt,              // [0]=Vcnt (pre-zeroed by memset)
    int* __restrict__ cmap, int* __restrict__ clsO,
    float4* __restrict__ sbx, float* __restrict__ sarea,
    int* __restrict__ scls, unsigned long long* __restrict__ skey)
{
#pragma clang fp contract(off)
    int gid = blockIdx.x * 256 + threadIdx.x;      // 0..65535
    int i = gid >> 3, s = gid & 7;
    const float4* lp = (const float4*)(logits + (size_t)i * NCLS);
    float best = -INFINITY; int bi = 0;
#pragma unroll
    for (int k2 = 0; k2 < 3; ++k2) {
        int c4 = s + 8 * k2;                       // 20 float4 chunks / 8 lanes
        if (c4 < 20) {
            float4 v = lp[c4]; int b = c4 * 4;
            if (v.x > best) { best = v.x; bi = b; }
            if (v.y > best) { best = v.y; bi = b + 1; }
            if (v.z > best) { best = v.z; bi = b + 2; }
            if (v.w > best) { best = v.w; bi = b + 3; }
        }
    }
    // 8-lane butterfly; ties -> lowest index (jnp first-max)
#pragma unroll
    for (int off = 1; off < 8; off <<= 1) {
        float ob = __shfl_xor(best, off, 8);
        int   oi = __shfl_xor(bi, off, 8);
        if (ob > best || (ob == best && oi < bi)) { best = ob; bi = oi; }
    }
    if (s == 0) {
        clsO[i] = bi;
        float c = conf[i];
        int cm = -1;
        if (c > 0.5f) {
            int cid = atomicAdd(&cnt[0], 1);
            cm = cid;
            float4 b = ((const float4*)box)[i];    // x, y, w, h
            float hw = b.z * 0.5f, hh = b.w * 0.5f;  // == w/2 exactly
            sbx[cid] = make_float4(b.x - hw, b.y - hh, b.x + hw, b.y + hh);
            sarea[cid] = b.z * b.w;
            scls[cid] = bi;
            // asc key <=> desc conf, duplicate conf tie-broken by orig index
            skey[cid] = ((unsigned long long)(unsigned)(~__float_as_uint(c)) << 32)
                        | (unsigned)i;
        }
        cmap[i] = cm;
    }
}

// ---------------- K2: candidates (branch-free) + edges + tail -----------
// 256x256 compact tiles, upper-tri 1D grid. Inner loop accumulates a
// candidate bitmask with NO branch and NO divide (pipelineable ds_reads,
// the R2-verified shape); rare candidates (~0.3%) then get the exact
// __fdiv_rn IoU test + directed-edge emit. Last finishing block runs the
// Jacobi fixpoint and writes all outputs.
__global__ void __launch_bounds__(256) k_main(
    const float4* __restrict__ sbx, const float* __restrict__ sarea,
    const int* __restrict__ scls, const unsigned long long* __restrict__ skey,
    int* __restrict__ cnt,              // [0]=Vcnt [1]=paircnt [2]=done
    unsigned int* __restrict__ pairs,
    const float* __restrict__ box, const float* __restrict__ conf,
    const int* __restrict__ clsO, const int* __restrict__ cmap,
    float* __restrict__ out)
{
#pragma clang fp contract(off)
    __shared__ float4 cb[256];
    __shared__ float  ca[256];
    __shared__ int    cc[256];
    __shared__ unsigned long long ck[256];
    int tid = threadIdx.x;
    int V = cnt[0];

    // decode upper-tri tile id -> (bi, bj), bj >= bi
    int rem = blockIdx.x, bi = 0;
    while (rem >= 32 - bi) { rem -= 32 - bi; ++bi; }
    int bj = bi + rem;
    int rbase = bi << 8, cbase = bj << 8;

    if (rbase < V && cbase < V) {
        int t = cbase + tid;                   // may exceed V: gated below
        cb[tid] = sbx[t]; ca[tid] = sarea[t];
        cc[tid] = scls[t]; ck[tid] = skey[t];
        __syncthreads();
        int r = rbase + tid;
        if (r < V) {
            float4 rb = sbx[r];
            float rar = sarea[r];
            int rcls = scls[r];
            unsigned long long rk = skey[r];
#pragma unroll
            for (int w = 0; w < 4; ++w) {
                unsigned long long cand = 0ULL;
                int k0 = w << 6;
                for (int k = 0; k < 64; ++k) {   // branch-free, divide-free
                    int idx = k0 + k;
                    int c = cbase + idx;
                    float4 c4 = cb[idx];
                    float iw = fminf(rb.z, c4.z) - fmaxf(rb.x, c4.x);
                    float ih = fminf(rb.w, c4.w) - fmaxf(rb.y, c4.y);
                    bool pc = (cc[idx] == rcls) & (c > r) & (c < V)
                            & (iw > 0.0f) & (ih > 0.0f);
                    cand |= ((unsigned long long)pc) << k;
                }
                while (cand) {                   // rare path (~0.3% of pairs)
                    int k = __builtin_ctzll(cand);
                    cand &= cand - 1;
                    int idx = k0 + k;
                    float4 c4 = cb[idx];
                    // exact float32 op order of the reference:
                    float iw = fminf(rb.z, c4.z) - fmaxf(rb.x, c4.x);
                    iw = fmaxf(iw, 0.0f);
                    float ih = fminf(rb.w, c4.w) - fmaxf(rb.y, c4.y);
                    ih = fmaxf(ih, 0.0f);
                    float inter = iw * ih;
                    float uni = rar + ca[idx] - inter;
                    float iou = __fdiv_rn(inter, uni);    // IEEE divide
                    if (iou > 0.5f) {
                        unsigned long long okey = ck[idx];
                        unsigned int c = (unsigned)(cbase + idx);
                        unsigned int e = (rk < okey)
                            ? (((unsigned)r << 13) | c)
                            : ((c << 13) | (unsigned)r);
                        int eidx = atomicAdd(&cnt[1], 1);
                        if (eidx < PAIR_CAP) pairs[eidx] = e;
                    }
                }
            }
        }
    }

    // ---- completion protocol: last block does the serial tail ----
    __shared__ int lastflag;
    __threadfence();                       // release pair writes
    __syncthreads();
    if (tid == 0) {
        int old = atomicAdd(&cnt[2], 1);
        lastflag = (old == K2_BLOCKS - 1);
    }
    __syncthreads();
    if (!lastflag) return;
    __threadfence();                       // acquire all blocks' pairs

    // ---- Jacobi fixpoint over sparse suppression DAG (LDS) ----
    // keep_{t+1}[v] = valid[v] & !exists edge u->v with keep_t[u]; edges
    // follow key order (DAG) => unique fixpoint == sequential greedy scan.
    __shared__ unsigned long long keep[NWD], sn[NWD];
    __shared__ int chg;
    int E = cnt[1]; if (E > PAIR_CAP) E = PAIR_CAP;
    int fullw = V >> 6, remv = V & 63;
    if (tid < NWD) {
        unsigned long long vm = (tid < fullw) ? ~0ULL
            : (tid == fullw && remv) ? ((1ULL << remv) - 1ULL) : 0ULL;
        keep[tid] = vm;                    // K0 = all compacted (valid)
    }
    __syncthreads();
    for (int round = 0; round < 8192; ++round) {
        if (tid < NWD) sn[tid] = 0ULL;
        if (tid == 0) chg = 0;
        __syncthreads();
        for (int e = tid; e < E; e += 256) {
            unsigned int p = pairs[e];
            int u = p >> 13, v = p & 8191;
            if ((keep[u >> 6] >> (u & 63)) & 1ULL)
                atomicOr(&sn[v >> 6], 1ULL << (v & 63));
        }
        __syncthreads();
        if (tid < NWD) {
            unsigned long long vm = (tid < fullw) ? ~0ULL
                : (tid == fullw && remv) ? ((1ULL << remv) - 1ULL) : 0ULL;
            unsigned long long nk = vm & ~sn[tid];
            if (nk != keep[tid]) { keep[tid] = nk; chg = 1; }
        }
        __syncthreads();
        if (!chg) break;
    }

    // ---- outputs (single block, L2-hot) ----
    for (int i = tid; i < N; i += 256) {
        int cm = cmap[i];
        float m = 0.0f;
        if (cm >= 0) m = (float)((keep[cm >> 6] >> (cm & 63)) & 1ULL);
        float4 b = ((const float4*)box)[i];
        out[i * 5 + 0] = b.x * m;
        out[i * 5 + 1] = b.y * m;
        out[i * 5 + 2] = b.z * m;
        out[i * 5 + 3] = b.w * m;
        out[i * 5 + 4] = conf[i] * m;
        out[5 * N + i] = (float)clsO[i];
        out[6 * N + i] = m;
    }
}

// ---------------- launch -------------------------------------------------
extern "C" void kernel_launch(void* const* d_in, const int* in_sizes, int n_in,
                              void* d_out, int out_size, void* d_ws, size_t ws_size,
                              hipStream_t stream) {
    const float* box    = (const float*)d_in[0];
    const float* conf   = (const float*)d_in[1];
    const float* logits = (const float*)d_in[2];
    float* out = (float*)d_out;

    char* ws = (char*)d_ws;
    int* cnt      = (int*)(ws + 0);                       // Vcnt/paircnt/done
    int* cmap     = (int*)(ws + 4096);                    // 32 KB
    int* clsO     = (int*)(ws + 36864);                   // 32 KB
    float* sarea  = (float*)(ws + 69632);                 // 32 KB
    int* scls     = (int*)(ws + 102400);                  // 32 KB
    unsigned long long* skey = (unsigned long long*)(ws + 135168);  // 64 KB
    float4* sbx   = (float4*)(ws + 262144);               // 128 KB
    unsigned int* pairs = (unsigned int*)(ws + 393216);   // 4 MB

    hipMemsetAsync(cnt, 0, 256, stream);
    k_prep<<<256, 256, 0, stream>>>(box, conf, logits, cnt, cmap, clsO,
                                    sbx, sarea, scls, skey);
    k_main<<<K2_BLOCKS, 256, 0, stream>>>(sbx, sarea, scls, skey, cnt, pairs,
                                          box, conf, clsO, cmap, out);
}